// Round 1
// baseline (1057.989 us; speedup 1.0000x reference)
//
#include <hip/hip_runtime.h>
#include <math.h>

// Sizes fixed by the problem.
#define Bb 32
#define Pp 1024
#define Nn 1024
#define Ee 128

static constexpr float INV_SQRT_E = 0.08838834764831845f;  // 1/sqrt(128)

__device__ __forceinline__ float fast_tanh(float x) {
  // tanh via exp(-2|x|): stable for all x, ~1e-7 rel error
  float ax = fabsf(x);
  float t = __expf(-2.0f * ax);
  float r = (1.0f - t) / (1.0f + t);
  return copysignf(r, x);
}

// K1: ekk[b,n,c] = exp(k)*v  (c<128)  |  exp(k)  (c>=128)
__global__ __launch_bounds__(256) void kv_kernel(const float* __restrict__ nodes,
                                                 const float* __restrict__ Wk,
                                                 const float* __restrict__ Wv,
                                                 float* __restrict__ ekk) {
  __shared__ float a[16 * 128];
  const int t = threadIdx.x;
  const long row0 = (long)blockIdx.x * 16;  // flat (b*N + n)
  for (int idx = t; idx < 2048; idx += 256) a[idx] = nodes[row0 * 128 + idx];
  __syncthreads();
  const int c = t & 127, g = t >> 7;
  float acck[8] = {}, accv[8] = {};
  for (int e = 0; e < 128; e += 4) {
    float wk0 = Wk[e * 128 + c], wk1 = Wk[(e + 1) * 128 + c];
    float wk2 = Wk[(e + 2) * 128 + c], wk3 = Wk[(e + 3) * 128 + c];
    float wv0 = Wv[e * 128 + c], wv1 = Wv[(e + 1) * 128 + c];
    float wv2 = Wv[(e + 2) * 128 + c], wv3 = Wv[(e + 3) * 128 + c];
#pragma unroll
    for (int i = 0; i < 8; i++) {
      const float4 av = *(const float4*)(&a[(g * 8 + i) * 128 + e]);
      acck[i] = fmaf(av.x, wk0, acck[i]);
      acck[i] = fmaf(av.y, wk1, acck[i]);
      acck[i] = fmaf(av.z, wk2, acck[i]);
      acck[i] = fmaf(av.w, wk3, acck[i]);
      accv[i] = fmaf(av.x, wv0, accv[i]);
      accv[i] = fmaf(av.y, wv1, accv[i]);
      accv[i] = fmaf(av.z, wv2, accv[i]);
      accv[i] = fmaf(av.w, wv3, accv[i]);
    }
  }
#pragma unroll
  for (int i = 0; i < 8; i++) {
    long r = row0 + g * 8 + i;
    float ekx = __expf(acck[i]);
    ekk[r * 256 + c] = ekx * accv[i];
    ekk[r * 256 + 128 + c] = ekx;
  }
}

// phase-1 helper: one of the three q GEMMs, accumulate into qa[8]
__device__ __forceinline__ void qgemm_pass(const float* __restrict__ mat,
                                           const float* __restrict__ w,
                                           float* __restrict__ a, long bp, int t,
                                           int c, int g, float qa[8]) {
  __syncthreads();
  for (int idx = t; idx < 2048; idx += 256) a[idx] = mat[bp * 128 + idx];
  __syncthreads();
  for (int e = 0; e < 128; e += 4) {
    float w0 = w[e * 128 + c], w1 = w[(e + 1) * 128 + c];
    float w2 = w[(e + 2) * 128 + c], w3 = w[(e + 3) * 128 + c];
#pragma unroll
    for (int i = 0; i < 8; i++) {
      const float4 av = *(const float4*)(&a[(g * 8 + i) * 128 + e]);
      qa[i] = fmaf(av.x, w0, qa[i]);
      qa[i] = fmaf(av.y, w1, qa[i]);
      qa[i] = fmaf(av.z, w2, qa[i]);
      qa[i] = fmaf(av.w, w3, qa[i]);
    }
  }
}

__global__ __launch_bounds__(256) void main_kernel(
    const float* __restrict__ nodes, const float* __restrict__ q1m,
    const float* __restrict__ q2m, const float* __restrict__ lnm,
    const float* __restrict__ loadv, const float* __restrict__ leftv,
    const float* __restrict__ cdist, const float* __restrict__ ninf,
    const float* __restrict__ Wq1, const float* __restrict__ Wq2,
    const float* __restrict__ Wql, const float* __restrict__ ekk,
    float* __restrict__ out, const float* __restrict__ sc_log_scale,
    const float* __restrict__ sc_aft_alpha,
    const float* __restrict__ sc_probs_alpha) {
  __shared__ float aft[16 * 128];   // AFT_out tile
  __shared__ float ubuf[1024 * 9];  // union: phase1 A-tile / phase2 e_bias / phase4 node chunk
  __shared__ float red[4][8];
  __shared__ float invs[16];

  const int t = threadIdx.x;
  const int j = blockIdx.x;
  // b-grouping swizzle: all 64 p-tiles of one b share blockIdx%8 -> same XCD L2
  const int b = (j & 7) + ((j >> 9) << 3);
  const int p0 = ((j >> 3) & 63) * 16;
  const long bp = (long)b * Pp + p0;
  const float log_scale = sc_log_scale[0];
  const float c1 = log_scale * sc_aft_alpha[0];
  const float c2 = log_scale * sc_probs_alpha[0];
  const int c = t & 127, g = t >> 7;

  // ---- phase 1: q = q1+q2+q_last, sigmoid (kept in regs)
  float qa[8] = {};
  qgemm_pass(q1m, Wq1, ubuf, bp, t, c, g, qa);
  qgemm_pass(q2m, Wq2, ubuf, bp, t, c, g, qa);
  qgemm_pass(lnm, Wql, ubuf, bp, t, c, g, qa);
#pragma unroll
  for (int i = 0; i < 8; i++) {
    int p = g * 8 + i;
    float ld = loadv[bp + p];
    float lf = leftv[bp + p];
    qa[i] = fmaf(ld, Wql[128 * 128 + c], qa[i]);
    qa[i] = fmaf(lf, Wql[129 * 128 + c], qa[i]);
    qa[i] = 1.0f / (1.0f + __expf(-qa[i]));  // sigmoid
  }

  // ---- phase 2: num/den = e_bias @ [ek*v, ek]
  float accn[8] = {}, accd[8] = {};
  for (int n0 = 0; n0 < Nn; n0 += 64) {
    __syncthreads();
    for (int idx = t; idx < 1024; idx += 256) {
      int r = idx >> 6, cc = idx & 63;
      long off = (bp + r) * (long)Nn + n0 + cc;
      ubuf[idx] = __expf(fmaf(-c1, cdist[off], ninf[off]));  // e_bias tile [16][64]
    }
    __syncthreads();
    for (int nn = 0; nn < 64; nn += 4) {
      const float* r0 = &ekk[((long)b * Nn + n0 + nn) * 256];
      float kv0 = r0[c], kk0 = r0[128 + c];
      float kv1 = r0[256 + c], kk1 = r0[256 + 128 + c];
      float kv2 = r0[512 + c], kk2 = r0[512 + 128 + c];
      float kv3 = r0[768 + c], kk3 = r0[768 + 128 + c];
#pragma unroll
      for (int i = 0; i < 8; i++) {
        const float4 e4 = *(const float4*)(&ubuf[(g * 8 + i) * 64 + nn]);
        accn[i] = fmaf(e4.x, kv0, accn[i]);
        accn[i] = fmaf(e4.y, kv1, accn[i]);
        accn[i] = fmaf(e4.z, kv2, accn[i]);
        accn[i] = fmaf(e4.w, kv3, accn[i]);
        accd[i] = fmaf(e4.x, kk0, accd[i]);
        accd[i] = fmaf(e4.y, kk1, accd[i]);
        accd[i] = fmaf(e4.z, kk2, accd[i]);
        accd[i] = fmaf(e4.w, kk3, accd[i]);
      }
    }
  }

  // ---- phase 3: AFT_out -> LDS
  __syncthreads();
#pragma unroll
  for (int i = 0; i < 8; i++)
    aft[(g * 8 + i) * 128 + c] = qa[i] * (accn[i] / (accd[i] + 1e-20f));
  // (the syncthreads inside the first phase-4 chunk covers the aft write->read dep)

  // ---- phase 4: score GEMM, 8 rows x 8 n per thread in regs
  const int ng = t & 127;
  float sc[8][8];
#pragma unroll
  for (int i = 0; i < 8; i++)
#pragma unroll
    for (int jj = 0; jj < 8; jj++) sc[i][jj] = 0.0f;

  for (int cc0 = 0; cc0 < 128; cc0 += 8) {
    __syncthreads();
    for (int idx = t; idx < 8192; idx += 256) {
      int n = idx >> 3, cc = idx & 7;
      ubuf[n * 9 + cc] = nodes[((long)b * Nn + n) * 128 + cc0 + cc];
    }
    __syncthreads();
#pragma unroll
    for (int cc = 0; cc < 8; cc++) {
      float av[8];
#pragma unroll
      for (int i = 0; i < 8; i++) av[i] = aft[(g * 8 + i) * 128 + cc0 + cc];
#pragma unroll
      for (int jj = 0; jj < 8; jj++) {
        float nv = ubuf[(ng + 128 * jj) * 9 + cc];
#pragma unroll
        for (int i = 0; i < 8; i++) sc[i][jj] = fmaf(av[i], nv, sc[i][jj]);
      }
    }
  }

  // ---- phase 5: scale + clip + exp (tanh clip bounds scores: no max-subtract needed)
  float rs[8] = {};
#pragma unroll
  for (int i = 0; i < 8; i++) {
#pragma unroll
    for (int jj = 0; jj < 8; jj++) {
      long off = (bp + g * 8 + i) * (long)Nn + ng + 128 * jj;
      float s = fmaf(sc[i][jj], INV_SQRT_E, -c2 * cdist[off]);
      s = 10.0f * fast_tanh(s) + ninf[off];
      float e = __expf(s);
      sc[i][jj] = e;
      rs[i] += e;
    }
  }

  // row-sum reduction across the 128 threads sharing each row group
  const int lane = t & 63;
  const int wv = t >> 6;
#pragma unroll
  for (int i = 0; i < 8; i++) {
    float v = rs[i];
    v += __shfl_down(v, 32);
    v += __shfl_down(v, 16);
    v += __shfl_down(v, 8);
    v += __shfl_down(v, 4);
    v += __shfl_down(v, 2);
    v += __shfl_down(v, 1);
    if (lane == 0) red[wv][i] = v;
  }
  __syncthreads();
  if (t < 16) {
    int gg = t >> 3;
    invs[t] = 1.0f / (red[gg * 2][t & 7] + red[gg * 2 + 1][t & 7]);
  }
  __syncthreads();

  // ---- normalize from registers, single coalesced write
#pragma unroll
  for (int i = 0; i < 8; i++) {
    float inv = invs[g * 8 + i];
#pragma unroll
    for (int jj = 0; jj < 8; jj++) {
      long off = (bp + g * 8 + i) * (long)Nn + ng + 128 * jj;
      out[off] = sc[i][jj] * inv;
    }
  }
}

extern "C" void kernel_launch(void* const* d_in, const int* in_sizes, int n_in,
                              void* d_out, int out_size, void* d_ws, size_t ws_size,
                              hipStream_t stream) {
  const float* nodes = (const float*)d_in[0];
  const float* q1m = (const float*)d_in[1];
  const float* q2m = (const float*)d_in[2];
  const float* lnm = (const float*)d_in[3];
  const float* loadv = (const float*)d_in[4];
  const float* leftv = (const float*)d_in[5];
  const float* cdist = (const float*)d_in[6];
  const float* logs = (const float*)d_in[7];
  const float* ninf = (const float*)d_in[8];
  const float* Wq1 = (const float*)d_in[9];
  const float* Wq2 = (const float*)d_in[10];
  const float* Wql = (const float*)d_in[11];
  const float* Wk = (const float*)d_in[12];
  const float* Wv = (const float*)d_in[13];
  const float* aalpha = (const float*)d_in[14];
  const float* palpha = (const float*)d_in[15];

  float* ekk = (float*)d_ws;  // [B][N][256] = 32 MB

  kv_kernel<<<Bb * Nn / 16, 256, 0, stream>>>(nodes, Wk, Wv, ekk);
  main_kernel<<<Bb * Pp / 16, 256, 0, stream>>>(
      nodes, q1m, q2m, lnm, loadv, leftv, cdist, ninf, Wq1, Wq2, Wql, ekk,
      (float*)d_out, logs, aalpha, palpha);
}

// Round 2
// 525.235 us; speedup vs baseline: 2.0143x; 2.0143x over previous
//
#include <hip/hip_runtime.h>
#include <math.h>

#define Bb 32
#define Pp 1024
#define Nn 1024
#define Ee 128

typedef unsigned short u16;
typedef __bf16 bf16x8 __attribute__((ext_vector_type(8)));
typedef float f32x4 __attribute__((ext_vector_type(4)));
typedef u16 us8 __attribute__((ext_vector_type(8)));
typedef _Float16 h8v __attribute__((ext_vector_type(8)));

#define MFMA __builtin_amdgcn_mfma_f32_16x16x32_bf16

static constexpr float INV_SQRT_E = 0.08838834764831845f;  // 1/sqrt(128)

__device__ __forceinline__ bf16x8 asbf(us8 v) { return __builtin_bit_cast(bf16x8, v); }

// split x into bf16 hi + bf16 lo (RTN), x ~= hi + lo to ~2^-17 rel
__device__ __forceinline__ void bsplit(float x, u16& h, u16& l) {
  unsigned u = __float_as_uint(x);
  unsigned r = u + 0x7FFF + ((u >> 16) & 1);
  h = (u16)(r >> 16);
  float hf = __uint_as_float((unsigned)h << 16);
  float lof = x - hf;
  unsigned u2 = __float_as_uint(lof);
  unsigned r2 = u2 + 0x7FFF + ((u2 >> 16) & 1);
  l = (u16)(r2 >> 16);
}

__device__ __forceinline__ float fast_tanh(float x) {
  float ax = fabsf(x);
  float t = __expf(-2.0f * ax);
  float r = (1.0f - t) / (1.0f + t);
  return copysignf(r, x);
}

// ---------------- K0: transposed split weight planes ----------------
// wcat[c][k], k in [0,384): rows of [Wq1;Wq2;Wql(0:128)].  wkv[c][k]: c<128 -> Wk[k][c], else Wv[k][c-128]
__global__ __launch_bounds__(256) void prep_weights(
    const float* __restrict__ Wq1, const float* __restrict__ Wq2,
    const float* __restrict__ Wql, const float* __restrict__ Wk,
    const float* __restrict__ Wv, u16* __restrict__ wcat_hi, u16* __restrict__ wcat_lo,
    u16* __restrict__ wkv_hi, u16* __restrict__ wkv_lo) {
  int t = threadIdx.x;
  if (blockIdx.x == 0) {
    for (int i = t; i < 128 * 384; i += 256) {
      int c = i / 384, k = i % 384;
      float v = (k < 128) ? Wq1[k * 128 + c]
                          : (k < 256) ? Wq2[(k - 128) * 128 + c] : Wql[(k - 256) * 128 + c];
      u16 h, l;
      bsplit(v, h, l);
      wcat_hi[i] = h;
      wcat_lo[i] = l;
    }
  } else {
    for (int i = t; i < 256 * 128; i += 256) {
      int c = i >> 7, k = i & 127;
      float v = (c < 128) ? Wk[k * 128 + c] : Wv[k * 128 + (c - 128)];
      u16 h, l;
      bsplit(v, h, l);
      wkv_hi[i] = h;
      wkv_lo[i] = l;
    }
  }
}

// ---------------- K1: k/v GEMM (split MFMA) -> ekkT planes + nodesP planes ----------------
// ekkT[b][c][n]: c<128 -> exp(k)*v, c>=128 -> exp(k).  nodesP[b][dgrp][n][8] = split(nodes[n][8*dgrp+j])
__global__ __launch_bounds__(256, 1) void kv_prep(
    const float* __restrict__ nodes, const u16* __restrict__ wkv_hi,
    const u16* __restrict__ wkv_lo, u16* __restrict__ ekkT_hi, u16* __restrict__ ekkT_lo,
    u16* __restrict__ nodesP_hi, u16* __restrict__ nodesP_lo) {
  __shared__ u16 a_hi[32 * 136], a_lo[32 * 136];
  __shared__ float kvbuf[32 * 264];
  const int t = threadIdx.x;
  const int b = blockIdx.x >> 5;
  const int n0 = (blockIdx.x & 31) * 32;
  // stage nodes tile, split
  for (int i = t; i < 4096; i += 256) {
    int n = i >> 7, d = i & 127;
    float v = nodes[((long)(b * 1024 + n0 + n)) * 128 + d];
    u16 h, l;
    bsplit(v, h, l);
    a_hi[n * 136 + d] = h;
    a_lo[n * 136 + d] = l;
  }
  __syncthreads();
  const int lane = t & 63, w = t >> 6;
  const int lr = lane & 15, lg = lane >> 4;
  f32x4 acc0[2][4] = {}, acc1[2][4] = {};
#pragma unroll
  for (int ks = 0; ks < 4; ++ks) {
    us8 ah[2], al[2];
#pragma unroll
    for (int mt = 0; mt < 2; ++mt) {
      int ro = (lr + 16 * mt) * 136 + ks * 32 + lg * 8;
      ah[mt] = *(const us8*)&a_hi[ro];
      al[mt] = *(const us8*)&a_lo[ro];
    }
    us8 bh[4], bl[4];
#pragma unroll
    for (int cc = 0; cc < 4; ++cc) {
      long off = (long)((w * 4 + cc) * 16 + lr) * 128 + ks * 32 + lg * 8;
      bh[cc] = *(const us8*)&wkv_hi[off];
      bl[cc] = *(const us8*)&wkv_lo[off];
    }
#pragma unroll
    for (int mt = 0; mt < 2; ++mt)
#pragma unroll
      for (int cc = 0; cc < 4; ++cc) {
        acc0[mt][cc] = MFMA(asbf(ah[mt]), asbf(bh[cc]), acc0[mt][cc], 0, 0, 0);
        acc1[mt][cc] = MFMA(asbf(al[mt]), asbf(bh[cc]), acc1[mt][cc], 0, 0, 0);
        acc1[mt][cc] = MFMA(asbf(ah[mt]), asbf(bl[cc]), acc1[mt][cc], 0, 0, 0);
      }
  }
#pragma unroll
  for (int mt = 0; mt < 2; ++mt)
#pragma unroll
    for (int cc = 0; cc < 4; ++cc) {
      int c = (w * 4 + cc) * 16 + lr;
#pragma unroll
      for (int r = 0; r < 4; ++r)
        kvbuf[(lg * 4 + r + 16 * mt) * 264 + c] = acc0[mt][cc][r] + acc1[mt][cc][r];
    }
  __syncthreads();
  // ekkT output (c-major rows, 64B chunks per row across 4 threads)
#pragma unroll
  for (int jo = 0; jo < 4; ++jo) {
    int j = jo * 64 + (t >> 2);
    int i4 = t & 3;
    int kcol = (j < 128) ? j : (j - 128);
    us8 h8, l8;
#pragma unroll
    for (int jj = 0; jj < 8; ++jj) {
      int n = i4 * 8 + jj;
      float kv = kvbuf[n * 264 + kcol];
      float ek = __expf(kv);
      float val = (j < 128) ? ek * kvbuf[n * 264 + j + 128] : ek;
      u16 h, l;
      bsplit(val, h, l);
      h8[jj] = h;
      l8[jj] = l;
    }
    long o = ((long)(b * 256 + j)) * 1024 + n0 + i4 * 8;
    *(us8*)&ekkT_hi[o] = h8;
    *(us8*)&ekkT_lo[o] = l8;
  }
  // nodesP output (8-d packed for 16B B-frag loads)
  {
    int pl = t >> 7, r = t & 127;
    int dgrp = r >> 3, nb = r & 7;
    const u16* src = pl ? a_lo : a_hi;
    u16* dst = pl ? nodesP_lo : nodesP_hi;
#pragma unroll
    for (int i = 0; i < 4; ++i) {
      int n = nb + 8 * i;
      us8 v = *(const us8*)&src[n * 136 + dgrp * 8];
      *(us8*)&dst[(((long)(b * 16 + dgrp)) * 1024 + n0 + n) * 8] = v;
    }
  }
}

// ---------------- main fused kernel: 16 p-rows per block, 512 threads ----------------
__global__ __launch_bounds__(512, 1) void main_kernel(
    const float* __restrict__ q1m, const float* __restrict__ q2m,
    const float* __restrict__ lnm, const float* __restrict__ loadv,
    const float* __restrict__ leftv, const float* __restrict__ cdist,
    const float* __restrict__ ninf, const float* __restrict__ Wql,
    const u16* __restrict__ wcat_hi, const u16* __restrict__ wcat_lo,
    const u16* __restrict__ ekkT_hi, const u16* __restrict__ ekkT_lo,
    const u16* __restrict__ nodesP_hi, const u16* __restrict__ nodesP_lo,
    float* __restrict__ out, const float* __restrict__ logs,
    const float* __restrict__ aal, const float* __restrict__ pal) {
  extern __shared__ char smem[];
  float* dbuf = (float*)smem;                   // [16][1032] f32: -c2*dist
  _Float16* nbuf = (_Float16*)(smem + 66048);   // [16][1032] f16: ninf
  u16* aft_hi = (u16*)(smem + 99072);           // [16][136]
  u16* aft_lo = (u16*)(smem + 103424);
  char* U = smem + 107776;                      // 49920B union region
  float* qbuf = (float*)U;                      // [16][132] sigmoid(q)
  float* c2buf = (float*)(U + 8448);            // [16][264] num|den
  u16* frag_hi = (u16*)(U + 25344);             // [12][64][8] A-frag staging
  u16* frag_lo = (u16*)(U + 37632);
  _Float16* expbuf = (_Float16*)U;              // [16][1032] alias (phase 5)
  float* psum = (float*)(smem + 157696);        // [16][32]
  float* invb = (float*)(smem + 159744);        // [16]

  const int t = threadIdx.x;
  const int lane = t & 63;
  const int w = t >> 6;
  const int lr = lane & 15, lg = lane >> 4;
  const int L = ((int)blockIdx.x & 7) * 256 + ((int)blockIdx.x >> 3);  // XCD swizzle
  const int b = L >> 6;
  const int p0 = (L & 63) * 16;
  const long bp = (long)b * Pp + p0;
  const float ls = logs[0];
  const float c1 = ls * aal[0];
  const float c2 = ls * pal[0];

  // ---- P1: q = [q1|q2|last]@Wcat (+load/left rank-2), sigmoid -> qbuf
  {
    const int p = t >> 5, kb = t & 31;
    const long rowb = (bp + p) * 128;
#pragma unroll
    for (int j = 0; j < 12; ++j) {
      int k = kb + 32 * j;
      float v = (j < 4) ? q1m[rowb + k] : (j < 8) ? q2m[rowb + k - 128] : lnm[rowb + k - 256];
      u16 h, l;
      bsplit(v, h, l);
      int fo = (j * 64 + (kb >> 3) * 16 + p) * 8 + (kb & 7);
      frag_hi[fo] = h;
      frag_lo[fo] = l;
    }
  }
  __syncthreads();
  {
    f32x4 q0 = {}, q1v = {};
#pragma unroll
    for (int ks = 0; ks < 12; ++ks) {
      us8 ah = *(const us8*)&frag_hi[(ks * 64 + lane) * 8];
      us8 al = *(const us8*)&frag_lo[(ks * 64 + lane) * 8];
      long bo = (long)(16 * w + lr) * 384 + ks * 32 + lg * 8;
      us8 bh = *(const us8*)&wcat_hi[bo];
      us8 bl = *(const us8*)&wcat_lo[bo];
      q0 = MFMA(asbf(ah), asbf(bh), q0, 0, 0, 0);
      q1v = MFMA(asbf(al), asbf(bh), q1v, 0, 0, 0);
      q1v = MFMA(asbf(ah), asbf(bl), q1v, 0, 0, 0);
    }
    int c = 16 * w + lr;
    float wl1 = Wql[128 * 128 + c], wl2 = Wql[129 * 128 + c];
#pragma unroll
    for (int r = 0; r < 4; ++r) {
      int row = lg * 4 + r;
      float qv = q0[r] + q1v[r] + loadv[bp + row] * wl1 + leftv[bp + row] * wl2;
      qbuf[row * 132 + c] = 1.0f / (1.0f + __expf(-qv));
    }
  }
  __syncthreads();

  // ---- P2: [num|den] = e_bias @ ekkT^T, e_bias built on the fly; stash -c2*dist & ninf
  {
    const int p = t >> 5, cb = t & 31;
    const long rowo = (bp + p) * (long)Nn;
    float dist[4], nf[4];
#pragma unroll
    for (int q = 0; q < 4; ++q) {
      dist[q] = cdist[rowo + cb + 32 * q];
      nf[q] = ninf[rowo + cb + 32 * q];
    }
    f32x4 aA[2] = {}, aB[2] = {};
    for (int s = 0; s < 8; ++s) {
      const int N0 = 128 * s;
      us8 BH[2][4], BL[2][4];  // prefetch B for this stage (L2-resident ekkT)
#pragma unroll
      for (int ct2 = 0; ct2 < 2; ++ct2) {
        long crow = ((long)(b * 256 + (w * 2 + ct2) * 16 + lr)) * 1024;
#pragma unroll
        for (int q = 0; q < 4; ++q) {
          long o = crow + N0 + 32 * q + lg * 8;
          BH[ct2][q] = *(const us8*)&ekkT_hi[o];
          BL[ct2][q] = *(const us8*)&ekkT_lo[o];
        }
      }
      const int sl = (s & 1) * 4;
#pragma unroll
      for (int q = 0; q < 4; ++q) {
        int n = N0 + cb + 32 * q;
        float u = fmaf(-c1, dist[q], nf[q]);
        float eb = __expf(u);
        dbuf[p * 1032 + n] = -c2 * dist[q];
        nbuf[p * 1032 + n] = (_Float16)nf[q];
        u16 h, l;
        bsplit(eb, h, l);
        int fo = ((sl + q) * 64 + (cb >> 3) * 16 + p) * 8 + (cb & 7);
        frag_hi[fo] = h;
        frag_lo[fo] = l;
      }
      if (s < 7) {
#pragma unroll
        for (int q = 0; q < 4; ++q) {
          dist[q] = cdist[rowo + 128 * (s + 1) + cb + 32 * q];
          nf[q] = ninf[rowo + 128 * (s + 1) + cb + 32 * q];
        }
      }
      __syncthreads();
#pragma unroll
      for (int q = 0; q < 4; ++q) {
        us8 ah = *(const us8*)&frag_hi[((sl + q) * 64 + lane) * 8];
        us8 al = *(const us8*)&frag_lo[((sl + q) * 64 + lane) * 8];
#pragma unroll
        for (int ct2 = 0; ct2 < 2; ++ct2) {
          aA[ct2] = MFMA(asbf(ah), asbf(BH[ct2][q]), aA[ct2], 0, 0, 0);
          aB[ct2] = MFMA(asbf(al), asbf(BH[ct2][q]), aB[ct2], 0, 0, 0);
          aB[ct2] = MFMA(asbf(ah), asbf(BL[ct2][q]), aB[ct2], 0, 0, 0);
        }
      }
      __syncthreads();
    }
#pragma unroll
    for (int ct2 = 0; ct2 < 2; ++ct2) {
      int c = (w * 2 + ct2) * 16 + lr;
#pragma unroll
      for (int r = 0; r < 4; ++r)
        c2buf[(lg * 4 + r) * 264 + c] = aA[ct2][r] + aB[ct2][r];
    }
  }
  __syncthreads();

  // ---- P3: AFT = sigmoid(q) * num/(den+1e-20) -> split bf16 LDS
  {
    int row = t >> 5, cb4 = (t & 31) * 4;
#pragma unroll
    for (int e = 0; e < 4; ++e) {
      int c = cb4 + e;
      float num = c2buf[row * 264 + c];
      float den = c2buf[row * 264 + 128 + c];
      float aftv = qbuf[row * 132 + c] * (num / (den + 1e-20f));
      u16 h, l;
      bsplit(aftv, h, l);
      aft_hi[row * 136 + c] = h;
      aft_lo[row * 136 + c] = l;
    }
  }
  __syncthreads();

  // ---- P4: score = AFT @ nodes^T (split MFMA), 8 n-tiles per wave
  f32x4 s0[8] = {}, s1[8] = {};
#pragma unroll
  for (int ks = 0; ks < 4; ++ks) {
    int d0 = 32 * ks;
    us8 ah = *(const us8*)&aft_hi[lr * 136 + d0 + lg * 8];
    us8 al = *(const us8*)&aft_lo[lr * 136 + d0 + lg * 8];
    us8 BH[8], BL[8];
#pragma unroll
    for (int jn = 0; jn < 8; ++jn) {
      long o = (((long)(b * 16 + ks * 4 + lg)) * 1024 + (8 * w + jn) * 16 + lr) * 8;
      BH[jn] = *(const us8*)&nodesP_hi[o];
      BL[jn] = *(const us8*)&nodesP_lo[o];
    }
#pragma unroll
    for (int jn = 0; jn < 8; ++jn) {
      s0[jn] = MFMA(asbf(ah), asbf(BH[jn]), s0[jn], 0, 0, 0);
      s1[jn] = MFMA(asbf(al), asbf(BH[jn]), s1[jn], 0, 0, 0);
      s1[jn] = MFMA(asbf(ah), asbf(BL[jn]), s1[jn], 0, 0, 0);
    }
  }

  // ---- P5a: scale+dist, 10*tanh, +ninf, exp -> f16 expbuf (tanh bounds logits <= 10)
#pragma unroll
  for (int jn = 0; jn < 8; ++jn) {
    int n = (8 * w + jn) * 16 + lr;
#pragma unroll
    for (int r = 0; r < 4; ++r) {
      int p = lg * 4 + r;
      float sv = fmaf(s0[jn][r] + s1[jn][r], INV_SQRT_E, dbuf[p * 1032 + n]);
      float t10 = 10.0f * fast_tanh(sv);
      float logit = t10 + (float)nbuf[p * 1032 + n];
      expbuf[p * 1032 + n] = (_Float16)__expf(logit);
    }
  }
  __syncthreads();

  // ---- P5b: row sums -> 1/sum
  {
    int row = t >> 5, seg = t & 31;
    float ssum = 0.f;
#pragma unroll
    for (int i = 0; i < 4; ++i) {
      h8v v = *(const h8v*)&expbuf[row * 1032 + seg * 32 + i * 8];
#pragma unroll
      for (int jj = 0; jj < 8; ++jj) ssum += (float)v[jj];
    }
    psum[row * 32 + seg] = ssum;
  }
  __syncthreads();
  if (t < 16) {
    float tot = 0.f;
    for (int i = 0; i < 32; ++i) tot += psum[t * 32 + i];
    invb[t] = 1.0f / tot;
  }
  __syncthreads();

  // ---- P5c: normalize, coalesced write
  {
    int row = t >> 5, cb = t & 31;
    float inv = invb[row];
    long ro = (bp + row) * (long)Nn;
#pragma unroll
    for (int k = 0; k < 8; ++k) {
      int n = cb * 4 + 128 * k;
      float4 o4;
      o4.x = (float)expbuf[row * 1032 + n] * inv;
      o4.y = (float)expbuf[row * 1032 + n + 1] * inv;
      o4.z = (float)expbuf[row * 1032 + n + 2] * inv;
      o4.w = (float)expbuf[row * 1032 + n + 3] * inv;
      *(float4*)&out[ro + n] = o4;
    }
  }
}

extern "C" void kernel_launch(void* const* d_in, const int* in_sizes, int n_in,
                              void* d_out, int out_size, void* d_ws, size_t ws_size,
                              hipStream_t stream) {
  const float* nodes = (const float*)d_in[0];
  const float* q1m = (const float*)d_in[1];
  const float* q2m = (const float*)d_in[2];
  const float* lnm = (const float*)d_in[3];
  const float* loadv = (const float*)d_in[4];
  const float* leftv = (const float*)d_in[5];
  const float* cdist = (const float*)d_in[6];
  const float* logs = (const float*)d_in[7];
  const float* ninf = (const float*)d_in[8];
  const float* Wq1 = (const float*)d_in[9];
  const float* Wq2 = (const float*)d_in[10];
  const float* Wql = (const float*)d_in[11];
  const float* Wk = (const float*)d_in[12];
  const float* Wv = (const float*)d_in[13];
  const float* aalpha = (const float*)d_in[14];
  const float* palpha = (const float*)d_in[15];

  char* ws = (char*)d_ws;
  u16* ekkT_hi = (u16*)ws;                            // 16 MB
  u16* ekkT_lo = (u16*)(ws + (16u << 20));            // 16 MB
  u16* nodesP_hi = (u16*)(ws + (32u << 20));          // 8 MB
  u16* nodesP_lo = (u16*)(ws + (40u << 20));          // 8 MB
  u16* wcat_hi = (u16*)(ws + (48u << 20));
  u16* wcat_lo = wcat_hi + 128 * 384;
  u16* wkv_hi = wcat_lo + 128 * 384;
  u16* wkv_lo = wkv_hi + 256 * 128;

  prep_weights<<<2, 256, 0, stream>>>(Wq1, Wq2, Wql, Wk, Wv, wcat_hi, wcat_lo, wkv_hi, wkv_lo);
  kv_prep<<<Bb * Nn / 32, 256, 0, stream>>>(nodes, wkv_hi, wkv_lo, ekkT_hi, ekkT_lo,
                                            nodesP_hi, nodesP_lo);

  const int LDS_TOTAL = 159808;
  hipFuncSetAttribute((const void*)main_kernel, hipFuncAttributeMaxDynamicSharedMemorySize,
                      LDS_TOTAL);
  main_kernel<<<Bb * Pp / 16, 512, LDS_TOTAL, stream>>>(
      q1m, q2m, lnm, loadv, leftv, cdist, ninf, Wql, wcat_hi, wcat_lo, ekkT_hi, ekkT_lo,
      nodesP_hi, nodesP_lo, (float*)d_out, logs, aalpha, palpha);
}

// Round 3
// 452.492 us; speedup vs baseline: 2.3381x; 1.1608x over previous
//
#include <hip/hip_runtime.h>
#include <math.h>

#define Bb 32
#define Pp 1024
#define Nn 1024
#define Ee 128

typedef unsigned short u16;
typedef __bf16 bf16x8 __attribute__((ext_vector_type(8)));
typedef float f32x4 __attribute__((ext_vector_type(4)));
typedef u16 us8 __attribute__((ext_vector_type(8)));
typedef _Float16 h8v __attribute__((ext_vector_type(8)));

#define MFMA __builtin_amdgcn_mfma_f32_16x16x32_bf16

static constexpr float INV_SQRT_E = 0.08838834764831845f;  // 1/sqrt(128)

__device__ __forceinline__ bf16x8 asbf(us8 v) { return __builtin_bit_cast(bf16x8, v); }

// split x into bf16 hi + bf16 lo (RTN), x ~= hi + lo to ~2^-17 rel
__device__ __forceinline__ void bsplit(float x, u16& h, u16& l) {
  unsigned u = __float_as_uint(x);
  unsigned r = u + 0x7FFF + ((u >> 16) & 1);
  h = (u16)(r >> 16);
  float hf = __uint_as_float((unsigned)h << 16);
  float lof = x - hf;
  unsigned u2 = __float_as_uint(lof);
  unsigned r2 = u2 + 0x7FFF + ((u2 >> 16) & 1);
  l = (u16)(r2 >> 16);
}

__device__ __forceinline__ float fast_tanh(float x) {
  float ax = fabsf(x);
  float t = __expf(-2.0f * ax);
  float r = (1.0f - t) / (1.0f + t);
  return copysignf(r, x);
}

// ---------------- K0: transposed split weight planes ----------------
__global__ __launch_bounds__(256) void prep_weights(
    const float* __restrict__ Wq1, const float* __restrict__ Wq2,
    const float* __restrict__ Wql, const float* __restrict__ Wk,
    const float* __restrict__ Wv, u16* __restrict__ wcat_hi, u16* __restrict__ wcat_lo,
    u16* __restrict__ wkv_hi, u16* __restrict__ wkv_lo) {
  int t = threadIdx.x;
  if (blockIdx.x == 0) {
    for (int i = t; i < 128 * 384; i += 256) {
      int c = i / 384, k = i % 384;
      float v = (k < 128) ? Wq1[k * 128 + c]
                          : (k < 256) ? Wq2[(k - 128) * 128 + c] : Wql[(k - 256) * 128 + c];
      u16 h, l;
      bsplit(v, h, l);
      wcat_hi[i] = h;
      wcat_lo[i] = l;
    }
  } else {
    for (int i = t; i < 256 * 128; i += 256) {
      int c = i >> 7, k = i & 127;
      float v = (c < 128) ? Wk[k * 128 + c] : Wv[k * 128 + (c - 128)];
      u16 h, l;
      bsplit(v, h, l);
      wkv_hi[i] = h;
      wkv_lo[i] = l;
    }
  }
}

// ---------------- K1: k/v GEMM (split MFMA) -> ekkT planes + nodesP planes ----------------
__global__ __launch_bounds__(256, 1) void kv_prep(
    const float* __restrict__ nodes, const u16* __restrict__ wkv_hi,
    const u16* __restrict__ wkv_lo, u16* __restrict__ ekkT_hi, u16* __restrict__ ekkT_lo,
    u16* __restrict__ nodesP_hi, u16* __restrict__ nodesP_lo) {
  __shared__ u16 a_hi[32 * 136], a_lo[32 * 136];
  __shared__ float kvbuf[32 * 264];
  const int t = threadIdx.x;
  const int b = blockIdx.x >> 5;
  const int n0 = (blockIdx.x & 31) * 32;
  for (int i = t; i < 4096; i += 256) {
    int n = i >> 7, d = i & 127;
    float v = nodes[((long)(b * 1024 + n0 + n)) * 128 + d];
    u16 h, l;
    bsplit(v, h, l);
    a_hi[n * 136 + d] = h;
    a_lo[n * 136 + d] = l;
  }
  __syncthreads();
  const int lane = t & 63, w = t >> 6;
  const int lr = lane & 15, lg = lane >> 4;
  f32x4 acc0[2][4] = {}, acc1[2][4] = {};
#pragma unroll
  for (int ks = 0; ks < 4; ++ks) {
    us8 ah[2], al[2];
#pragma unroll
    for (int mt = 0; mt < 2; ++mt) {
      int ro = (lr + 16 * mt) * 136 + ks * 32 + lg * 8;
      ah[mt] = *(const us8*)&a_hi[ro];
      al[mt] = *(const us8*)&a_lo[ro];
    }
    us8 bh[4], bl[4];
#pragma unroll
    for (int cc = 0; cc < 4; ++cc) {
      long off = (long)((w * 4 + cc) * 16 + lr) * 128 + ks * 32 + lg * 8;
      bh[cc] = *(const us8*)&wkv_hi[off];
      bl[cc] = *(const us8*)&wkv_lo[off];
    }
#pragma unroll
    for (int mt = 0; mt < 2; ++mt)
#pragma unroll
      for (int cc = 0; cc < 4; ++cc) {
        acc0[mt][cc] = MFMA(asbf(ah[mt]), asbf(bh[cc]), acc0[mt][cc], 0, 0, 0);
        acc1[mt][cc] = MFMA(asbf(al[mt]), asbf(bh[cc]), acc1[mt][cc], 0, 0, 0);
        acc1[mt][cc] = MFMA(asbf(ah[mt]), asbf(bl[cc]), acc1[mt][cc], 0, 0, 0);
      }
  }
#pragma unroll
  for (int mt = 0; mt < 2; ++mt)
#pragma unroll
    for (int cc = 0; cc < 4; ++cc) {
      int c = (w * 4 + cc) * 16 + lr;
#pragma unroll
      for (int r = 0; r < 4; ++r)
        kvbuf[(lg * 4 + r + 16 * mt) * 264 + c] = acc0[mt][cc][r] + acc1[mt][cc][r];
    }
  __syncthreads();
#pragma unroll
  for (int jo = 0; jo < 4; ++jo) {
    int j = jo * 64 + (t >> 2);
    int i4 = t & 3;
    int kcol = (j < 128) ? j : (j - 128);
    us8 h8, l8;
#pragma unroll
    for (int jj = 0; jj < 8; ++jj) {
      int n = i4 * 8 + jj;
      float kv = kvbuf[n * 264 + kcol];
      float ek = __expf(kv);
      float val = (j < 128) ? ek * kvbuf[n * 264 + j + 128] : ek;
      u16 h, l;
      bsplit(val, h, l);
      h8[jj] = h;
      l8[jj] = l;
    }
    long o = ((long)(b * 256 + j)) * 1024 + n0 + i4 * 8;
    *(us8*)&ekkT_hi[o] = h8;
    *(us8*)&ekkT_lo[o] = l8;
  }
  {
    int pl = t >> 7, r = t & 127;
    int dgrp = r >> 3, nb = r & 7;
    const u16* src = pl ? a_lo : a_hi;
    u16* dst = pl ? nodesP_lo : nodesP_hi;
#pragma unroll
    for (int i = 0; i < 4; ++i) {
      int n = nb + 8 * i;
      us8 v = *(const us8*)&src[n * 136 + dgrp * 8];
      *(us8*)&dst[(((long)(b * 16 + dgrp)) * 1024 + n0 + n) * 8] = v;
    }
  }
}

// ---------------- main fused kernel: 16 p-rows per block, 512 threads ----------------
// LDS 60736 B static -> 2 blocks/CU; VGPR capped 128 via launch_bounds(512,4).
__global__ __launch_bounds__(512, 4) void main_kernel(
    const float* __restrict__ q1m, const float* __restrict__ q2m,
    const float* __restrict__ lnm, const float* __restrict__ loadv,
    const float* __restrict__ leftv, const float* __restrict__ cdist,
    const float* __restrict__ ninf, const float* __restrict__ Wql,
    const u16* __restrict__ wcat_hi, const u16* __restrict__ wcat_lo,
    const u16* __restrict__ ekkT_hi, const u16* __restrict__ ekkT_lo,
    const u16* __restrict__ nodesP_hi, const u16* __restrict__ nodesP_lo,
    float* __restrict__ out, const float* __restrict__ logs,
    const float* __restrict__ aal, const float* __restrict__ pal) {
  __shared__ __align__(16) char smem_raw[60736];
  float* qbuf = (float*)smem_raw;               // [16][132]
  float* c2buf = (float*)(smem_raw + 8448);     // [16][264] num|den
  u16* frag_hi = (u16*)(smem_raw + 25344);      // [12][64][8]
  u16* frag_lo = (u16*)(smem_raw + 37632);
  _Float16* expbuf = (_Float16*)smem_raw;       // [16][1032] alias (P5)
  u16* aft_hi = (u16*)(smem_raw + 49920);       // [16][136]
  u16* aft_lo = (u16*)(smem_raw + 54272);
  float* psum = (float*)(smem_raw + 58624);     // [16][32]
  float* invb = (float*)(smem_raw + 60672);     // [16]

  const int t = threadIdx.x;
  const int lane = t & 63;
  const int w = t >> 6;
  const int lr = lane & 15, lg = lane >> 4;
  const int L = ((int)blockIdx.x & 7) * 256 + ((int)blockIdx.x >> 3);  // XCD swizzle
  const int b = L >> 6;
  const int p0 = (L & 63) * 16;
  const long bp = (long)b * Pp + p0;
  const float ls = logs[0];
  const float c1 = ls * aal[0];
  const float c2 = ls * pal[0];

  // ---- P1: q = [q1|q2|last]@Wcat (+load/left rank-2), sigmoid -> qbuf
  {
    const int p = t >> 5, kb = t & 31;
    const long rowb = (bp + p) * 128;
#pragma unroll
    for (int j = 0; j < 12; ++j) {
      int k = kb + 32 * j;
      float v = (j < 4) ? q1m[rowb + k] : (j < 8) ? q2m[rowb + k - 128] : lnm[rowb + k - 256];
      u16 h, l;
      bsplit(v, h, l);
      int fo = (j * 64 + (kb >> 3) * 16 + p) * 8 + (kb & 7);
      frag_hi[fo] = h;
      frag_lo[fo] = l;
    }
  }
  __syncthreads();
  {
    f32x4 q0 = {}, q1v = {};
#pragma unroll
    for (int ks = 0; ks < 12; ++ks) {
      us8 ah = *(const us8*)&frag_hi[(ks * 64 + lane) * 8];
      us8 al = *(const us8*)&frag_lo[(ks * 64 + lane) * 8];
      long bo = (long)(16 * w + lr) * 384 + ks * 32 + lg * 8;
      us8 bh = *(const us8*)&wcat_hi[bo];
      us8 bl = *(const us8*)&wcat_lo[bo];
      q0 = MFMA(asbf(ah), asbf(bh), q0, 0, 0, 0);
      q1v = MFMA(asbf(al), asbf(bh), q1v, 0, 0, 0);
      q1v = MFMA(asbf(ah), asbf(bl), q1v, 0, 0, 0);
    }
    int c = 16 * w + lr;
    float wl1 = Wql[128 * 128 + c], wl2 = Wql[129 * 128 + c];
#pragma unroll
    for (int r = 0; r < 4; ++r) {
      int row = lg * 4 + r;
      float qv = q0[r] + q1v[r] + loadv[bp + row] * wl1 + leftv[bp + row] * wl2;
      qbuf[row * 132 + c] = 1.0f / (1.0f + __expf(-qv));
    }
  }
  __syncthreads();

  // ---- P2: [num|den] = e_bias @ ekkT^T; 1 barrier/stage, dbuffed frag slots
  {
    const int p = t >> 5, cb = t & 31;
    const long rowo = (bp + p) * (long)Nn;
    float dist[4], nf[4];
#pragma unroll
    for (int q = 0; q < 4; ++q) {
      dist[q] = cdist[rowo + cb + 32 * q];
      nf[q] = ninf[rowo + cb + 32 * q];
    }
    // prologue: eb(0) -> slots 0..3
#pragma unroll
    for (int q = 0; q < 4; ++q) {
      float eb = __expf(fmaf(-c1, dist[q], nf[q]));
      u16 h, l;
      bsplit(eb, h, l);
      int fo = (q * 64 + (cb >> 3) * 16 + p) * 8 + (cb & 7);
      frag_hi[fo] = h;
      frag_lo[fo] = l;
    }
#pragma unroll
    for (int q = 0; q < 4; ++q) {  // dist for stage 1
      dist[q] = cdist[rowo + 128 + cb + 32 * q];
      nf[q] = ninf[rowo + 128 + cb + 32 * q];
    }
    __syncthreads();
    f32x4 aA[2] = {}, aB[2] = {};
    for (int s = 0; s < 8; ++s) {
      const int N0 = 128 * s;
      us8 BH[2][4], BL[2][4];
#pragma unroll
      for (int ct2 = 0; ct2 < 2; ++ct2) {
        long crow = ((long)(b * 256 + (w * 2 + ct2) * 16 + lr)) * 1024;
#pragma unroll
        for (int q = 0; q < 4; ++q) {
          long o = crow + N0 + 32 * q + lg * 8;
          BH[ct2][q] = *(const us8*)&ekkT_hi[o];
          BL[ct2][q] = *(const us8*)&ekkT_lo[o];
        }
      }
      if (s < 7) {  // prep eb(s+1) into the other slot half (overlaps MFMA(s))
        const int sl2 = ((s + 1) & 1) * 4;
#pragma unroll
        for (int q = 0; q < 4; ++q) {
          float eb = __expf(fmaf(-c1, dist[q], nf[q]));
          u16 h, l;
          bsplit(eb, h, l);
          int fo = ((sl2 + q) * 64 + (cb >> 3) * 16 + p) * 8 + (cb & 7);
          frag_hi[fo] = h;
          frag_lo[fo] = l;
        }
        if (s < 6) {
#pragma unroll
          for (int q = 0; q < 4; ++q) {
            dist[q] = cdist[rowo + 128 * (s + 2) + cb + 32 * q];
            nf[q] = ninf[rowo + 128 * (s + 2) + cb + 32 * q];
          }
        }
      }
      const int sl = (s & 1) * 4;
#pragma unroll
      for (int q = 0; q < 4; ++q) {
        us8 ah = *(const us8*)&frag_hi[((sl + q) * 64 + lane) * 8];
        us8 al = *(const us8*)&frag_lo[((sl + q) * 64 + lane) * 8];
#pragma unroll
        for (int ct2 = 0; ct2 < 2; ++ct2) {
          aA[ct2] = MFMA(asbf(ah), asbf(BH[ct2][q]), aA[ct2], 0, 0, 0);
          aB[ct2] = MFMA(asbf(al), asbf(BH[ct2][q]), aB[ct2], 0, 0, 0);
          aB[ct2] = MFMA(asbf(ah), asbf(BL[ct2][q]), aB[ct2], 0, 0, 0);
        }
      }
      __syncthreads();
    }
#pragma unroll
    for (int ct2 = 0; ct2 < 2; ++ct2) {
      int c = (w * 2 + ct2) * 16 + lr;
#pragma unroll
      for (int r = 0; r < 4; ++r)
        c2buf[(lg * 4 + r) * 264 + c] = aA[ct2][r] + aB[ct2][r];
    }
  }
  __syncthreads();

  // ---- P3: AFT = sigmoid(q) * num/(den+1e-20) -> split bf16 LDS
  {
    int row = t >> 5, cb4 = (t & 31) * 4;
#pragma unroll
    for (int e = 0; e < 4; ++e) {
      int c = cb4 + e;
      float num = c2buf[row * 264 + c];
      float den = c2buf[row * 264 + 128 + c];
      float aftv = qbuf[row * 132 + c] * (num / (den + 1e-20f));
      u16 h, l;
      bsplit(aftv, h, l);
      aft_hi[row * 136 + c] = h;
      aft_lo[row * 136 + c] = l;
    }
  }
  __syncthreads();

  // ---- P4: score = AFT @ nodes^T (split MFMA), 8 n-tiles per wave
  f32x4 s0[8] = {}, s1[8] = {};
#pragma unroll
  for (int ks = 0; ks < 4; ++ks) {
    int d0 = 32 * ks;
    us8 ah = *(const us8*)&aft_hi[lr * 136 + d0 + lg * 8];
    us8 al = *(const us8*)&aft_lo[lr * 136 + d0 + lg * 8];
    us8 BH[8], BL[8];
#pragma unroll
    for (int jn = 0; jn < 8; ++jn) {
      long o = (((long)(b * 16 + ks * 4 + lg)) * 1024 + (8 * w + jn) * 16 + lr) * 8;
      BH[jn] = *(const us8*)&nodesP_hi[o];
      BL[jn] = *(const us8*)&nodesP_lo[o];
    }
#pragma unroll
    for (int jn = 0; jn < 8; ++jn) {
      s0[jn] = MFMA(asbf(ah), asbf(BH[jn]), s0[jn], 0, 0, 0);
      s1[jn] = MFMA(asbf(al), asbf(BH[jn]), s1[jn], 0, 0, 0);
      s1[jn] = MFMA(asbf(ah), asbf(BL[jn]), s1[jn], 0, 0, 0);
    }
  }

  // ---- P5a: scale + dist bias (re-read global) + tanh-clip + exp -> f16 expbuf
#pragma unroll
  for (int jn = 0; jn < 8; ++jn) {
    int n = (8 * w + jn) * 16 + lr;
#pragma unroll
    for (int r = 0; r < 4; ++r) {
      int p = lg * 4 + r;
      long off = (bp + p) * (long)Nn + n;
      float sv = fmaf(s0[jn][r] + s1[jn][r], INV_SQRT_E, -c2 * cdist[off]);
      float t10 = 10.0f * fast_tanh(sv);
      float logit = t10 + ninf[off];
      expbuf[p * 1032 + n] = (_Float16)__expf(logit);
    }
  }
  __syncthreads();

  // ---- P5b: row sums -> 1/sum
  {
    int row = t >> 5, seg = t & 31;
    float ssum = 0.f;
#pragma unroll
    for (int i = 0; i < 4; ++i) {
      h8v v = *(const h8v*)&expbuf[row * 1032 + seg * 32 + i * 8];
#pragma unroll
      for (int jj = 0; jj < 8; ++jj) ssum += (float)v[jj];
    }
    psum[row * 32 + seg] = ssum;
  }
  __syncthreads();
  if (t < 16) {
    float tot = 0.f;
    for (int i = 0; i < 32; ++i) tot += psum[t * 32 + i];
    invb[t] = 1.0f / tot;
  }
  __syncthreads();

  // ---- P5c: normalize, coalesced write
  {
    int row = t >> 5, cb = t & 31;
    float inv = invb[row];
    long ro = (bp + row) * (long)Nn;
#pragma unroll
    for (int k = 0; k < 8; ++k) {
      int n = cb * 4 + 128 * k;
      float4 o4;
      o4.x = (float)expbuf[row * 1032 + n] * inv;
      o4.y = (float)expbuf[row * 1032 + n + 1] * inv;
      o4.z = (float)expbuf[row * 1032 + n + 2] * inv;
      o4.w = (float)expbuf[row * 1032 + n + 3] * inv;
      *(float4*)&out[ro + n] = o4;
    }
  }
}

extern "C" void kernel_launch(void* const* d_in, const int* in_sizes, int n_in,
                              void* d_out, int out_size, void* d_ws, size_t ws_size,
                              hipStream_t stream) {
  const float* nodes = (const float*)d_in[0];
  const float* q1m = (const float*)d_in[1];
  const float* q2m = (const float*)d_in[2];
  const float* lnm = (const float*)d_in[3];
  const float* loadv = (const float*)d_in[4];
  const float* leftv = (const float*)d_in[5];
  const float* cdist = (const float*)d_in[6];
  const float* logs = (const float*)d_in[7];
  const float* ninf = (const float*)d_in[8];
  const float* Wq1 = (const float*)d_in[9];
  const float* Wq2 = (const float*)d_in[10];
  const float* Wql = (const float*)d_in[11];
  const float* Wk = (const float*)d_in[12];
  const float* Wv = (const float*)d_in[13];
  const float* aalpha = (const float*)d_in[14];
  const float* palpha = (const float*)d_in[15];

  char* ws = (char*)d_ws;
  u16* ekkT_hi = (u16*)ws;                            // 16 MB
  u16* ekkT_lo = (u16*)(ws + (16u << 20));            // 16 MB
  u16* nodesP_hi = (u16*)(ws + (32u << 20));          // 8 MB
  u16* nodesP_lo = (u16*)(ws + (40u << 20));          // 8 MB
  u16* wcat_hi = (u16*)(ws + (48u << 20));
  u16* wcat_lo = wcat_hi + 128 * 384;
  u16* wkv_hi = wcat_lo + 128 * 384;
  u16* wkv_lo = wkv_hi + 256 * 128;

  prep_weights<<<2, 256, 0, stream>>>(Wq1, Wq2, Wql, Wk, Wv, wcat_hi, wcat_lo, wkv_hi, wkv_lo);
  kv_prep<<<Bb * Nn / 32, 256, 0, stream>>>(nodes, wkv_hi, wkv_lo, ekkT_hi, ekkT_lo,
                                            nodesP_hi, nodesP_lo);
  main_kernel<<<Bb * Pp / 16, 512, 0, stream>>>(
      q1m, q2m, lnm, loadv, leftv, cdist, ninf, Wql, wcat_hi, wcat_lo, ekkT_hi, ekkT_lo,
      nodesP_hi, nodesP_lo, (float*)d_out, logs, aalpha, palpha);
}